// Round 10
// baseline (352.427 us; speedup 1.0000x reference)
//
#include <hip/hip_runtime.h>
#include <stdint.h>

typedef unsigned short u16;
typedef uint8_t u8;
typedef __attribute__((ext_vector_type(8))) short short8;
typedef __attribute__((ext_vector_type(4))) float f32x4;
typedef __attribute__((ext_vector_type(4))) int i32x4;

#define EPSF 1e-5f
#define LGKM0 asm volatile("s_waitcnt lgkmcnt(0)" ::: "memory")
#define VM0   asm volatile("s_waitcnt vmcnt(0)" ::: "memory")
#define VM4   asm volatile("s_waitcnt vmcnt(4)" ::: "memory")
#define BAR   __builtin_amdgcn_s_barrier()
#define GLL(src, dst) __builtin_amdgcn_global_load_lds(                     \
    (const __attribute__((address_space(1))) void*)(src),                   \
    (__attribute__((address_space(3))) void*)(dst), 16, 0, 0)

__device__ __forceinline__ u16 f2bf(float f) {
  uint32_t u = __float_as_uint(f);
  u += 0x7FFFu + ((u >> 16) & 1u);
  return (u16)(u >> 16);
}
__device__ __forceinline__ u8 sgn8(float y) {
  return y > 0.f ? (u8)1 : (y < 0.f ? (u8)0xFF : (u8)0);
}

// ---------------- BN1 stats (x is NCHW f32: 32,128,64,64) ----------------
__global__ void bn1_stage1(const float* __restrict__ x, float* __restrict__ p1) {
  int c = blockIdx.x >> 2, s = blockIdx.x & 3;
  int tid = threadIdx.x;
  float sum = 0.f, sq = 0.f;
  for (int n = s * 8; n < s * 8 + 8; ++n) {
    const f32x4* bp = (const f32x4*)(x + (((size_t)(n * 128 + c)) << 12));
    #pragma unroll 4
    for (int i = tid; i < 1024; i += 256) {
      f32x4 v = bp[i];
      sum += v[0] + v[1] + v[2] + v[3];
      sq  += v[0]*v[0] + v[1]*v[1] + v[2]*v[2] + v[3]*v[3];
    }
  }
  __shared__ float rs[256], rq[256];
  rs[tid] = sum; rq[tid] = sq; __syncthreads();
  for (int st = 128; st > 0; st >>= 1) {
    if (tid < st) { rs[tid] += rs[tid + st]; rq[tid] += rq[tid + st]; }
    __syncthreads();
  }
  if (tid == 0) { p1[blockIdx.x] = rs[0]; p1[512 + blockIdx.x] = rq[0]; }
}

__global__ void bn1_stage2(const float* __restrict__ p1, const float* __restrict__ g,
                           const float* __restrict__ b, float* __restrict__ sc,
                           float* __restrict__ off) {
  int c = threadIdx.x; // 128 threads
  float s = 0.f, q = 0.f;
  for (int k = 0; k < 4; ++k) { s += p1[c * 4 + k]; q += p1[512 + c * 4 + k]; }
  float mean = s * (1.f / 131072.f);
  float var  = q * (1.f / 131072.f) - mean * mean;
  float is = rsqrtf(var + EPSF);
  float scv = g[c] * is;
  sc[c] = scv;
  off[c] = b[c] - mean * scv;
}

// ---------------- BN2 stage2: reduce per-block partials ----------------
__global__ void bn2_stage2b(const float* __restrict__ pS, const float* __restrict__ pQ,
                            const float* __restrict__ g, const float* __restrict__ bb,
                            float* __restrict__ sc, float* __restrict__ off) {
  int o = blockIdx.x, t = threadIdx.x;
  __shared__ float rs[256], rq[256];
  const float* ps = pS + (size_t)o * 1024;
  const float* pq = pQ + (size_t)o * 1024;
  float s = ps[t] + ps[t + 256] + ps[t + 512] + ps[t + 768];
  float q = pq[t] + pq[t + 256] + pq[t + 512] + pq[t + 768];
  rs[t] = s; rq[t] = q; __syncthreads();
  for (int st = 128; st > 0; st >>= 1) {
    if (t < st) { rs[t] += rs[t + st]; rq[t] += rq[t + st]; }
    __syncthreads();
  }
  if (t == 0) {
    float mean = rs[0] * (1.f / 131072.f);
    float var  = rq[0] * (1.f / 131072.f) - mean * mean;
    float is = rsqrtf(var + EPSF);
    float scv = g[o] * is;
    sc[o] = scv;
    off[o] = bb[o] - mean * scv;
  }
}

// ---------------- weight prep ----------------
__device__ __forceinline__ float blk_reduce(float v, float* red) {
  int t = threadIdx.x;
  red[t] = v; __syncthreads();
  for (int st = 128; st > 0; st >>= 1) {
    if (t < st) red[t] += red[t + st];
    __syncthreads();
  }
  float r = red[0]; __syncthreads();
  return r;
}

// Lane-major reg-fragment packs.
// i8: wr[st][rg][lane][64B]: byte ((st*4+rg)*64 + (k>>4)*16 + li)*64 + nf*16 + (k&15)
//     holds sign(w[o=rg*64+nf*16+li][ch]) for the step's 64-ch slice.
//     conv1: st=tap*2+cc, ch=cc*64+k. conv2: st=c2*18+tap*2+cc, ch=c2*128+cc*64+k.
// skip bf16: wskr[e][rg][lane][64 u16]: u16 ((e*4+rg)*64 + kq*16+li)*64 + (ks*4+nf)*8 + j
//     holds sign(wsk[o][e*64 + ks*32 + kq*8 + j]) * ask/alpha2.
__global__ void prep_weights(const float* __restrict__ w1, const float* __restrict__ w2,
                             const float* __restrict__ wsk, u8* __restrict__ w1r,
                             u8* __restrict__ w2r, u16* __restrict__ wskr,
                             float* __restrict__ alpha1, float* __restrict__ alpha2) {
  int o = blockIdx.x, t = threadIdx.x;
  int rg = o >> 6, nf = (o >> 4) & 3, li = o & 15;
  __shared__ float red[256];
  float s = 0.f;
  for (int j = t; j < 1152; j += 256) s += fabsf(w1[(size_t)o * 1152 + j]);
  float a1 = blk_reduce(s, red) * (1.f / 1152.f);
  if (t == 0) alpha1[o] = a1;
  for (int j = t; j < 1152; j += 256) {
    int st = j >> 6, k = j & 63;
    int tap = st >> 1, cc = st & 1;
    int ch = cc * 64 + k;
    size_t idx = ((size_t)((st * 4 + rg) * 64 + (k >> 4) * 16 + li)) * 64 +
                 nf * 16 + (k & 15);
    w1r[idx] = sgn8(w1[(size_t)o * 1152 + ch * 9 + tap]);
  }
  s = 0.f;
  for (int j = t; j < 2304; j += 256) s += fabsf(w2[(size_t)o * 2304 + j]);
  float a2 = blk_reduce(s, red) * (1.f / 2304.f);
  if (t == 0) alpha2[o] = a2;
  for (int j = t; j < 2304; j += 256) {
    int st = j >> 6, k = j & 63;
    int c2 = st / 18, r = st % 18, tap = r >> 1, cc = r & 1;
    int ch = c2 * 128 + cc * 64 + k;
    size_t idx = ((size_t)((st * 4 + rg) * 64 + (k >> 4) * 16 + li)) * 64 +
                 nf * 16 + (k & 15);
    w2r[idx] = sgn8(w2[(size_t)o * 2304 + ch * 9 + tap]);
  }
  s = 0.f;
  for (int j = t; j < 128; j += 256) s += fabsf(wsk[o * 128 + j]);
  float ask = blk_reduce(s, red) * (1.f / 128.f);
  float ratio = ask / a2;
  for (int j = t; j < 128; j += 256) {
    int e = j >> 6, c = j & 63;
    int ks = c >> 5, kq = (c >> 3) & 3, jj = c & 7;
    float w = wsk[o * 128 + j];
    float v = w > 0.f ? ratio : (w < 0.f ? -ratio : 0.f);
    wskr[((size_t)((e * 4 + rg) * 64 + kq * 16 + li)) * 64 + (ks * 4 + nf) * 8 + jj] =
        f2bf(v);
  }
}

// ---------------- temb = t @ tw^T + tb ----------------
__global__ void temb_k(const float* __restrict__ t, const float* __restrict__ tw,
                       const float* __restrict__ tb, float* __restrict__ temb) {
  int bb = blockIdx.x, o = threadIdx.x;
  __shared__ float tl[512];
  tl[o] = t[bb * 512 + o];
  tl[o + 256] = t[bb * 512 + 256 + o];
  __syncthreads();
  float acc = tb[o];
  #pragma unroll 8
  for (int k = 0; k < 512; ++k) acc += tl[k] * tw[(size_t)o * 512 + k];
  temb[bb * 256 + o] = acc;
}

// ------- border zero: 96 i8 planes of [66][66][128], borders only -------
__global__ void border_zero(u8* __restrict__ Abuf) {
  u8* plane = Abuf + (size_t)blockIdx.x * 557568;
  int tid = threadIdx.x;
  i32x4 z = {};
  for (int idx = tid; idx < 260; idx += 256) {
    int row, px;
    if (idx < 66) { row = 0; px = idx; }
    else if (idx < 132) { row = 65; px = idx - 66; }
    else { int e = idx - 132; row = 1 + (e >> 1); px = (e & 1) * 65; }
    u8* p = plane + (size_t)(row * 66 + px) * 128;
    #pragma unroll
    for (int i = 0; i < 8; ++i) *(i32x4*)(p + i * 16) = z;
  }
}

// -------- binact1: x NCHW -> a1p i8 planes [b][66][66][128] + xb bf16 [m][128] --------
__global__ void binact1(const float* __restrict__ x, const float* __restrict__ sc,
                        const float* __restrict__ off, u8* __restrict__ a1p,
                        u16* __restrict__ xb) {
  int b = blockIdx.x >> 6, y = blockIdx.x & 63, tid = threadIdx.x;
  __shared__ u8  ls[64 * 144];
  __shared__ u16 lx[64 * 136];
  int c = tid >> 1, x0 = (tid & 1) * 32;
  const float* src = x + (((size_t)(b * 128 + c)) << 12) + y * 64 + x0;
  float s0 = sc[c], o0 = off[c];
  #pragma unroll
  for (int i = 0; i < 32; i += 4) {
    f32x4 v = *(const f32x4*)(src + i);
    #pragma unroll
    for (int j = 0; j < 4; ++j) {
      int xc = x0 + i + j;
      float yv = s0 * v[j] + o0;
      ls[xc * 144 + c] = sgn8(yv);
      lx[xc * 136 + c] = f2bf(v[j]);
    }
  }
  __syncthreads();
  int xx = tid >> 2, cg = (tid & 3) * 32;
  u8*  pdst = a1p + ((size_t)b * 4356 + (y + 1) * 66 + xx + 1) * 128 + cg;
  u16* xdst = xb + ((size_t)blockIdx.x * 64 + xx) * 128 + cg;
  *(i32x4*)(pdst)      = *(const i32x4*)&ls[xx * 144 + cg];
  *(i32x4*)(pdst + 16) = *(const i32x4*)&ls[xx * 144 + cg + 16];
  #pragma unroll
  for (int i = 0; i < 32; i += 8)
    *(i32x4*)(xdst + i) = *(const i32x4*)&lx[xx * 136 + cg + i];
}

// -------- binact2: h [m][256] f32 -> a2p i8 planes [b*2+c2][66][66][128] --------
__global__ void binact2(const float* __restrict__ h, const float* __restrict__ sc,
                        const float* __restrict__ off, u8* __restrict__ a2p) {
  int b = blockIdx.x >> 6, y = blockIdx.x & 63, tid = threadIdx.x;
  __shared__ float s_sc[256], s_off[256];
  s_sc[tid] = sc[tid]; s_off[tid] = off[tid];
  __syncthreads();
  const f32x4* src = (const f32x4*)(h + (size_t)blockIdx.x * 16384);
  #pragma unroll 4
  for (int i = tid; i < 4096; i += 256) {
    f32x4 v = src[i];
    int px = i >> 6, c0 = (i & 63) * 4;
    int c2 = c0 >> 7, chm = c0 & 127;
    uint32_t p = (uint32_t)sgn8(s_sc[c0 + 0] * v[0] + s_off[c0 + 0]) |
                 ((uint32_t)sgn8(s_sc[c0 + 1] * v[1] + s_off[c0 + 1]) << 8) |
                 ((uint32_t)sgn8(s_sc[c0 + 2] * v[2] + s_off[c0 + 2]) << 16) |
                 ((uint32_t)sgn8(s_sc[c0 + 3] * v[3] + s_off[c0 + 3]) << 24);
    u8* dst = a2p + ((size_t)(b * 2 + c2) * 4356 + (y + 1) * 66 + px + 1) * 128 + chm;
    *(uint32_t*)dst = p;
  }
}

// ---------------- i8 implicit-GEMM conv, barrier-free main loop ----------------
// M=128, N=256, 512 thr = 8 waves (2M x 4N), 66.5 KB LDS, 2 blocks/CU.
// A: [4][66][128ch] i8 window in LDS (pre-swizzled-source GLL), read-only after
//    load -> conv1 loop has ZERO barriers; conv2 has 2 per 18-step chunk.
// B: per-lane 64B contiguous fragments (lane-major pack), loaded global->reg
//    one step ahead with counted vmcnt(4). No B in LDS, no per-step barrier.
template <int NCHUNK, bool SKIP, bool ADD_TEMB, bool STATS, bool DIRECT>
__global__ __launch_bounds__(512, 4) void convk(
    const u8* __restrict__ Apl, const u16* __restrict__ xb,
    const u8* __restrict__ wB, const u16* __restrict__ wskr,
    const float* __restrict__ alpha, const float* __restrict__ temb,
    float* __restrict__ outp, float* __restrict__ pS, float* __restrict__ pQ) {
  constexpr int NS = NCHUNK * 18;
  __shared__ u8 smem[66560];
  u8* lA = smem;            // 33792 B window; rest is epilogue scratch
  const int tid = threadIdx.x;
  const int lane = tid & 63, w = tid >> 6, wm = w >> 2, wn = w & 3;
  const int kq = lane >> 4, li = lane & 15;

  const int bid = blockIdx.x;
  const int tile = (bid & 7) * 128 + (bid >> 3);   // XCD-chunked swizzle
  const int m0 = tile * 128;
  const int b = m0 >> 12, row0 = (m0 >> 6) & 63;

  // ---- B: per-lane register fragments, double-slot ----
  i32x4 rB[2][4];
  const i32x4* wlane = (const i32x4*)(wB + ((size_t)wn * 64 + lane) * 64);
  auto loadB = [&](int s, int slot) {
    const i32x4* src = wlane + (size_t)s * 1024;  // step stride 16384 B = 1024 i32x4
    #pragma unroll
    for (int i = 0; i < 4; ++i) rB[slot][i] = src[i];
  };

  // ---- A window: 2112 granules, linear dest + pre-swizzled source ----
  auto winLoad = [&](int c) {
    const u8* gp = Apl + (size_t)(b * NCHUNK + c) * 557568 + (size_t)row0 * 8448;
    #pragma unroll
    for (int k = 0; k < 4; ++k) {
      int g = tid + k * 512;
      int row = g / 528, rem = g - row * 528;
      int px = rem >> 3, sl = rem & 7;
      const u8* src = gp + (size_t)(row * 66 + px) * 128 + ((sl ^ (px & 7)) << 4);
      u8* dst = lA + (size_t)((tid & ~63) + k * 512) * 16;
      GLL(src, dst);
    }
    if (tid < 64) {
      int g = 2048 + tid;
      int rem = g - 3 * 528;           // row 3
      int px = rem >> 3, sl = rem & 7;
      const u8* src = gp + (size_t)(3 * 66 + px) * 128 + ((sl ^ (px & 7)) << 4);
      u8* dst = lA + (size_t)2048 * 16;
      GLL(src, dst);
    }
  };

  // ---- A fragment base pointers ----
  const u8* pA[3][2];
  #pragma unroll
  for (int dx = 0; dx < 3; ++dx)
    #pragma unroll
    for (int cc = 0; cc < 2; ++cc)
      pA[dx][cc] = lA + (size_t)wm * 8448 + (li + dx) * 128 +
                   ((((cc << 2) + kq) ^ ((li + dx) & 7)) << 4);

  i32x4 acc[4][4] = {};

  auto compute = [&](int dy, int dx, int cc, int slot) {
    i32x4 av[4];
    #pragma unroll
    for (int f = 0; f < 4; ++f)
      av[f] = *(const i32x4*)(pA[dx][cc] + dy * 8448 + f * 2048);
    __builtin_amdgcn_s_setprio(1);
    #pragma unroll
    for (int mf = 0; mf < 4; ++mf)
      #pragma unroll
      for (int nf = 0; nf < 4; ++nf)
        acc[mf][nf] = __builtin_amdgcn_mfma_i32_16x16x64_i8(
            av[mf], rB[slot][nf], acc[mf][nf], 0, 0, 0);
    __builtin_amdgcn_s_setprio(0);
  };

  // ---- prologue: A chunk 0 + B(0) ----
  winLoad(0);
  loadB(0, 0);
  VM4;                 // window landed (B(0) may still be in flight)
  BAR;

  // ---- main loop: no barriers (conv1); 2 per chunk boundary (conv2) ----
  #pragma unroll
  for (int s = 0; s < NS; ++s) {
    const int t = s % 18, cc = t & 1, tap = t >> 1;
    if (s + 1 < NS) { loadB(s + 1, (s + 1) & 1); VM4; } else { VM0; }
    compute(tap / 3, tap % 3, cc, s & 1);
    if (NCHUNK > 1 && t == 17 && s + 1 < NS) {
      LGKM0; BAR;                 // all waves done reading this window
      winLoad((s + 1) / 18);
      VM0; BAR;                   // new window published (B(s+1) also landed)
    }
  }

  f32x4 facc[4][4];
  if constexpr (SKIP) {
    #pragma unroll
    for (int mf = 0; mf < 4; ++mf)
      #pragma unroll
      for (int nf = 0; nf < 4; ++nf)
        #pragma unroll
        for (int r = 0; r < 4; ++r)
          facc[mf][nf][r] = (float)acc[mf][nf][r];
    const u8* pAs[2];
    #pragma unroll
    for (int ks = 0; ks < 2; ++ks)
      pAs[ks] = lA + (wm * 64 + li) * 128 + ((((ks << 2) + kq) ^ (li & 7)) << 4);
    LGKM0; BAR;                   // lA free to overwrite
    #pragma unroll
    for (int e = 0; e < 2; ++e) {
      // stage skip-A (xb, pre-swizzled source) into lA
      #pragma unroll
      for (int k = 0; k < 2; ++k) {
        int g = tid + k * 512;
        int m = g >> 3, sl = g & 7;
        const u8* src = (const u8*)xb + (size_t)(m0 + m) * 256 + e * 128 +
                        ((sl ^ (m & 7)) << 4);
        u8* dst = lA + (size_t)((tid & ~63) + k * 512) * 16;
        GLL(src, dst);
      }
      // skip-B lane-major fragments -> regs
      const u16* bbase = wskr + ((size_t)(e * 4 + wn) * 64 + lane) * 64;
      short8 sb[8];
      #pragma unroll
      for (int i = 0; i < 8; ++i) sb[i] = *(const short8*)(bbase + i * 8);
      VM0; BAR;
      #pragma unroll
      for (int ks = 0; ks < 2; ++ks) {
        short8 av[4];
        #pragma unroll
        for (int f = 0; f < 4; ++f) av[f] = *(const short8*)(pAs[ks] + f * 2048);
        __builtin_amdgcn_s_setprio(1);
        #pragma unroll
        for (int mf = 0; mf < 4; ++mf)
          #pragma unroll
          for (int nf = 0; nf < 4; ++nf)
            facc[mf][nf] = __builtin_amdgcn_mfma_f32_16x16x32_bf16(
                av[mf], sb[ks * 4 + nf], facc[mf][nf], 0, 0, 0);
        __builtin_amdgcn_s_setprio(0);
      }
      if (e == 0) { LGKM0; BAR; }
    }
  }

  const int cb = wn * 64 + li;

  if constexpr (STATS) {
    // per-block BN2 partials from registers (deterministic)
    float als[4], tas[4];
    #pragma unroll
    for (int nf = 0; nf < 4; ++nf) {
      int o = cb + nf * 16;
      als[nf] = alpha[o];
      tas[nf] = ADD_TEMB ? temb[b * 256 + o] : 0.f;
    }
    float ps[4] = {0.f, 0.f, 0.f, 0.f}, pq[4] = {0.f, 0.f, 0.f, 0.f};
    #pragma unroll
    for (int nf = 0; nf < 4; ++nf)
      #pragma unroll
      for (int mf = 0; mf < 4; ++mf)
        #pragma unroll
        for (int r = 0; r < 4; ++r) {
          float v = (float)acc[mf][nf][r] * als[nf] + tas[nf];
          ps[nf] += v; pq[nf] += v * v;
        }
    #pragma unroll
    for (int nf = 0; nf < 4; ++nf) {
      ps[nf] += __shfl_xor(ps[nf], 16); ps[nf] += __shfl_xor(ps[nf], 32);
      pq[nf] += __shfl_xor(pq[nf], 16); pq[nf] += __shfl_xor(pq[nf], 32);
    }
    float* reds = (float*)smem;        // [2][256]
    float* redq = reds + 512;
    __syncthreads();
    if (lane < 16) {
      #pragma unroll
      for (int nf = 0; nf < 4; ++nf) {
        reds[wm * 256 + wn * 64 + nf * 16 + lane] = ps[nf];
        redq[wm * 256 + wn * 64 + nf * 16 + lane] = pq[nf];
      }
    }
    __syncthreads();
    if (tid < 256) {
      pS[(size_t)tid * 1024 + bid] = reds[tid] + reds[256 + tid];
      pQ[(size_t)tid * 1024 + bid] = redq[tid] + redq[256 + tid];
    }
    __syncthreads();
    // restage h tile through LDS for full-line coalesced stores
    float* ld = (float*)smem;          // [64][256] granule-XOR swizzled
    #pragma unroll 1
    for (int p = 0; p < 2; ++p) {
      if (wm == p) {
        #pragma unroll
        for (int nf = 0; nf < 4; ++nf) {
          int colg0 = (cb + nf * 16) >> 2, c3 = li & 3;
          #pragma unroll
          for (int mf = 0; mf < 4; ++mf)
            #pragma unroll
            for (int r = 0; r < 4; ++r) {
              int rloc = mf * 16 + 4 * kq + r;
              float v = (float)acc[mf][nf][r] * als[nf] + tas[nf];
              ld[rloc * 256 + ((colg0 ^ kq) << 2) + c3] = v;
            }
        }
      }
      __syncthreads();
      #pragma unroll
      for (int it = 0; it < 8; ++it) {
        int flat = tid + it * 512;
        int row = flat >> 6, c4 = flat & 63;
        int c4p = c4 ^ ((row >> 2) & 3);
        f32x4 v = *(const f32x4*)&ld[row * 256 + c4p * 4];
        *(f32x4*)(outp + (size_t)(m0 + p * 64 + row) * 256 + c4 * 4) = v;
      }
      __syncthreads();
    }
  } else if constexpr (DIRECT) {
    // NCHW transpose epilogue: [128 m][65] tile, swizzled cols, coalesced stores
    float* tb2 = (float*)lA;
    float* obase = outp + (((size_t)(b * 256)) << 12) + (m0 & 4095);
    __syncthreads();
    #pragma unroll 1
    for (int c4 = 0; c4 < 4; ++c4) {
      if (wn == c4) {
        #pragma unroll
        for (int nf = 0; nf < 4; ++nf) {
          float al = alpha[c4 * 64 + nf * 16 + li];
          #pragma unroll
          for (int mf = 0; mf < 4; ++mf) {
            int cs = (li + nf * 16) ^ ((wm * 2 + (mf >> 1)) & 3);
            #pragma unroll
            for (int r = 0; r < 4; ++r)
              tb2[(wm * 64 + mf * 16 + 4 * kq + r) * 65 + cs] =
                  facc[mf][nf][r] * al;
          }
        }
      }
      __syncthreads();
      #pragma unroll
      for (int it = 0; it < 4; ++it) {
        int flat = tid + it * 512;
        int ch = flat >> 5, mg = flat & 31;
        int chs = ch ^ ((mg >> 3) & 3);
        f32x4 v;
        #pragma unroll
        for (int e = 0; e < 4; ++e) v[e] = tb2[(mg * 4 + e) * 65 + chs];
        *(f32x4*)(obase + (((size_t)(c4 * 64 + ch)) << 12) + mg * 4) = v;
      }
      __syncthreads();
    }
  }
}

extern "C" void kernel_launch(void* const* d_in, const int* in_sizes, int n_in,
                              void* d_out, int out_size, void* d_ws, size_t ws_size,
                              hipStream_t stream) {
  const float* x      = (const float*)d_in[0];
  const float* t      = (const float*)d_in[1];
  const float* w1     = (const float*)d_in[2];
  const float* w2     = (const float*)d_in[3];
  const float* wskip  = (const float*)d_in[4];
  const float* gamma1 = (const float*)d_in[5];
  const float* beta1  = (const float*)d_in[6];
  const float* gamma2 = (const float*)d_in[7];
  const float* beta2  = (const float*)d_in[8];
  const float* tw     = (const float*)d_in[9];
  const float* tb     = (const float*)d_in[10];
  float* out = (float*)d_out;

  uint8_t* base = (uint8_t*)d_ws;
  size_t off = 0;
  auto alloc = [&](size_t bytes) {
    void* p = base + off;
    off += (bytes + 255) & ~(size_t)255;
    return p;
  };
  // 96 i8 planes of [66][66][128]: first 32 = a1p, next 64 = a2p
  u8* Abuf     = (u8*)alloc((size_t)96 * 557568);
  u8* a1p      = Abuf;
  u8* a2p      = Abuf + (size_t)32 * 557568;
  u16* xb      = (u16*)alloc((size_t)131072 * 128 * 2);
  float* h     = (float*)alloc((size_t)131072 * 256 * 4);
  u8* w1r      = (u8*)alloc((size_t)18 * 16384);
  u8* w2r      = (u8*)alloc((size_t)36 * 16384);
  u16* wskr    = (u16*)alloc((size_t)2 * 16384 * 2);
  float* temb  = (float*)alloc(32 * 256 * 4);
  float* alpha1 = (float*)alloc(256 * 4);
  float* alpha2 = (float*)alloc(256 * 4);
  float* p1    = (float*)alloc(1024 * 4);
  float* pS    = (float*)alloc((size_t)256 * 1024 * 4);
  float* pQ    = (float*)alloc((size_t)256 * 1024 * 4);
  float* sc1   = (float*)alloc(128 * 4);
  float* off1  = (float*)alloc(128 * 4);
  float* sc2   = (float*)alloc(256 * 4);
  float* off2  = (float*)alloc(256 * 4);

  border_zero<<<96, 256, 0, stream>>>(Abuf);

  bn1_stage1<<<512, 256, 0, stream>>>(x, p1);
  bn1_stage2<<<1, 128, 0, stream>>>(p1, gamma1, beta1, sc1, off1);
  prep_weights<<<256, 256, 0, stream>>>(w1, w2, wskip, w1r, w2r, wskr, alpha1, alpha2);
  temb_k<<<32, 256, 0, stream>>>(t, tw, tb, temb);
  binact1<<<2048, 256, 0, stream>>>(x, sc1, off1, a1p, xb);

  // conv1: i8, barrier-free loop, writes h + BN2 per-block partials
  convk<1, false, true, true, false><<<1024, 512, 0, stream>>>(
      a1p, xb, w1r, (const u16*)nullptr, alpha1, temb, h, pS, pQ);

  bn2_stage2b<<<256, 256, 0, stream>>>(pS, pQ, gamma2, beta2, sc2, off2);
  binact2<<<2048, 256, 0, stream>>>(h, sc2, off2, a2p);

  // conv2: i8 + bf16 skip tail, direct NCHW output
  convk<2, true, false, false, true><<<1024, 512, 0, stream>>>(
      a2p, xb, w2r, wskr, alpha2, (const float*)nullptr, out,
      (float*)nullptr, (float*)nullptr);

  (void)in_sizes; (void)n_in; (void)out_size; (void)ws_size;
}

// Round 11
// 288.981 us; speedup vs baseline: 1.2195x; 1.2195x over previous
//
#include <hip/hip_runtime.h>
#include <stdint.h>

typedef unsigned short u16;
typedef uint8_t u8;
typedef __attribute__((ext_vector_type(8))) short short8;
typedef __attribute__((ext_vector_type(4))) float f32x4;
typedef __attribute__((ext_vector_type(4))) int i32x4;

#define EPSF 1e-5f
#define LGKM0 asm volatile("s_waitcnt lgkmcnt(0)" ::: "memory")
#define VM0   asm volatile("s_waitcnt vmcnt(0)" ::: "memory")
#define VM4   asm volatile("s_waitcnt vmcnt(4)" ::: "memory")
#define BAR   __builtin_amdgcn_s_barrier()
#define GLL(src, dst) __builtin_amdgcn_global_load_lds(                     \
    (const __attribute__((address_space(1))) void*)(src),                   \
    (__attribute__((address_space(3))) void*)(dst), 16, 0, 0)

__device__ __forceinline__ u16 f2bf(float f) {
  uint32_t u = __float_as_uint(f);
  u += 0x7FFFu + ((u >> 16) & 1u);
  return (u16)(u >> 16);
}
__device__ __forceinline__ u8 sgn8(float y) {
  return y > 0.f ? (u8)1 : (y < 0.f ? (u8)0xFF : (u8)0);
}

// ---------------- BN1 stats (x is NCHW f32: 32,128,64,64) ----------------
__global__ void bn1_stage1(const float* __restrict__ x, float* __restrict__ p1) {
  int c = blockIdx.x >> 2, s = blockIdx.x & 3;
  int tid = threadIdx.x;
  float sum = 0.f, sq = 0.f;
  for (int n = s * 8; n < s * 8 + 8; ++n) {
    const f32x4* bp = (const f32x4*)(x + (((size_t)(n * 128 + c)) << 12));
    #pragma unroll 4
    for (int i = tid; i < 1024; i += 256) {
      f32x4 v = bp[i];
      sum += v[0] + v[1] + v[2] + v[3];
      sq  += v[0]*v[0] + v[1]*v[1] + v[2]*v[2] + v[3]*v[3];
    }
  }
  __shared__ float rs[256], rq[256];
  rs[tid] = sum; rq[tid] = sq; __syncthreads();
  for (int st = 128; st > 0; st >>= 1) {
    if (tid < st) { rs[tid] += rs[tid + st]; rq[tid] += rq[tid + st]; }
    __syncthreads();
  }
  if (tid == 0) { p1[blockIdx.x] = rs[0]; p1[512 + blockIdx.x] = rq[0]; }
}

__global__ void bn1_stage2(const float* __restrict__ p1, const float* __restrict__ g,
                           const float* __restrict__ b, float* __restrict__ sc,
                           float* __restrict__ off) {
  int c = threadIdx.x; // 128 threads
  float s = 0.f, q = 0.f;
  for (int k = 0; k < 4; ++k) { s += p1[c * 4 + k]; q += p1[512 + c * 4 + k]; }
  float mean = s * (1.f / 131072.f);
  float var  = q * (1.f / 131072.f) - mean * mean;
  float is = rsqrtf(var + EPSF);
  float scv = g[c] * is;
  sc[c] = scv;
  off[c] = b[c] - mean * scv;
}

// ---------------- BN2 stage2: reduce per-block partials [2048][256] ----------------
__global__ void bn2_stage2b(const float* __restrict__ pS, const float* __restrict__ pQ,
                            const float* __restrict__ g, const float* __restrict__ bb,
                            float* __restrict__ sc, float* __restrict__ off) {
  int o = blockIdx.x, t = threadIdx.x;
  __shared__ float rs[256], rq[256];
  float s = 0.f, q = 0.f;
  #pragma unroll
  for (int k = 0; k < 8; ++k) {
    size_t j = t + k * 256;
    s += pS[j * 256 + o];
    q += pQ[j * 256 + o];
  }
  rs[t] = s; rq[t] = q; __syncthreads();
  for (int st = 128; st > 0; st >>= 1) {
    if (t < st) { rs[t] += rs[t + st]; rq[t] += rq[t + st]; }
    __syncthreads();
  }
  if (t == 0) {
    float mean = rs[0] * (1.f / 131072.f);
    float var  = rq[0] * (1.f / 131072.f) - mean * mean;
    float is = rsqrtf(var + EPSF);
    float scv = g[o] * is;
    sc[o] = scv;
    off[o] = bb[o] - mean * scv;
  }
}

// ---------------- weight prep ----------------
__device__ __forceinline__ float blk_reduce(float v, float* red) {
  int t = threadIdx.x;
  red[t] = v; __syncthreads();
  for (int st = 128; st > 0; st >>= 1) {
    if (t < st) red[t] += red[t + st];
    __syncthreads();
  }
  float r = red[0]; __syncthreads();
  return r;
}

// i8 step blocks packed for region-owned global_load_lds:
// byte(st, rg, g, j) with g = (o_loc<<2) + ((k>>4) ^ (o_loc&3)), j = k&15
// holds w[o = rg*64+o_loc][k] for the step's 64-ch slice.
// conv1: st = tap*2+cc (cc halves of 128ch). conv2: st = c2*18 + tap*2 + cc.
// wskB u16 [2][256][64]: sign(wsk)*ask/alpha2 in bf16 (granule-linear o*64+k).
__global__ void prep_weights(const float* __restrict__ w1, const float* __restrict__ w2,
                             const float* __restrict__ wsk, u8* __restrict__ w1s,
                             u8* __restrict__ w2s, u16* __restrict__ wskB,
                             float* __restrict__ alpha1, float* __restrict__ alpha2) {
  int o = blockIdx.x, t = threadIdx.x;
  int rg = o >> 6, ol = o & 63;
  __shared__ float red[256];
  float s = 0.f;
  for (int j = t; j < 1152; j += 256) s += fabsf(w1[(size_t)o * 1152 + j]);
  float a1 = blk_reduce(s, red) * (1.f / 1152.f);
  if (t == 0) alpha1[o] = a1;
  for (int j = t; j < 1152; j += 256) {
    int st = j >> 6, k = j & 63;
    int tap = st >> 1, cc = st & 1;
    int ch = cc * 64 + k;
    int g = (ol << 2) + ((k >> 4) ^ (ol & 3));
    w1s[(size_t)st * 16384 + rg * 4096 + g * 16 + (k & 15)] =
        sgn8(w1[(size_t)o * 1152 + ch * 9 + tap]);
  }
  s = 0.f;
  for (int j = t; j < 2304; j += 256) s += fabsf(w2[(size_t)o * 2304 + j]);
  float a2 = blk_reduce(s, red) * (1.f / 2304.f);
  if (t == 0) alpha2[o] = a2;
  for (int j = t; j < 2304; j += 256) {
    int st = j >> 6, k = j & 63;
    int c2 = st / 18, r = st % 18, tap = r >> 1, cc = r & 1;
    int ch = c2 * 128 + cc * 64 + k;
    int g = (ol << 2) + ((k >> 4) ^ (ol & 3));
    w2s[(size_t)st * 16384 + rg * 4096 + g * 16 + (k & 15)] =
        sgn8(w2[(size_t)o * 2304 + ch * 9 + tap]);
  }
  s = 0.f;
  for (int j = t; j < 128; j += 256) s += fabsf(wsk[o * 128 + j]);
  float ask = blk_reduce(s, red) * (1.f / 128.f);
  float ratio = ask / a2;
  for (int j = t; j < 128; j += 256) {
    int e = j >> 6, k = j & 63;
    float w = wsk[o * 128 + j];
    float v = w > 0.f ? ratio : (w < 0.f ? -ratio : 0.f);
    wskB[(size_t)e * 16384 + o * 64 + k] = f2bf(v);
  }
}

// ---------------- temb = t @ tw^T + tb ----------------
__global__ void temb_k(const float* __restrict__ t, const float* __restrict__ tw,
                       const float* __restrict__ tb, float* __restrict__ temb) {
  int bb = blockIdx.x, o = threadIdx.x;
  __shared__ float tl[512];
  tl[o] = t[bb * 512 + o];
  tl[o + 256] = t[bb * 512 + 256 + o];
  __syncthreads();
  float acc = tb[o];
  #pragma unroll 8
  for (int k = 0; k < 512; ++k) acc += tl[k] * tw[(size_t)o * 512 + k];
  temb[bb * 256 + o] = acc;
}

// ------- border zero: 96 i8 planes of [66][66][128], borders only -------
__global__ void border_zero(u8* __restrict__ Abuf) {
  u8* plane = Abuf + (size_t)blockIdx.x * 557568;
  int tid = threadIdx.x;
  i32x4 z = {};
  for (int idx = tid; idx < 260; idx += 256) {
    int row, px;
    if (idx < 66) { row = 0; px = idx; }
    else if (idx < 132) { row = 65; px = idx - 66; }
    else { int e = idx - 132; row = 1 + (e >> 1); px = (e & 1) * 65; }
    u8* p = plane + (size_t)(row * 66 + px) * 128;
    #pragma unroll
    for (int i = 0; i < 8; ++i) *(i32x4*)(p + i * 16) = z;
  }
}

// -------- binact1: x NCHW -> a1p i8 planes [b][66][66][128] + xb bf16 [m][128] --------
__global__ void binact1(const float* __restrict__ x, const float* __restrict__ sc,
                        const float* __restrict__ off, u8* __restrict__ a1p,
                        u16* __restrict__ xb) {
  int b = blockIdx.x >> 6, y = blockIdx.x & 63, tid = threadIdx.x;
  __shared__ u8  ls[64 * 144];
  __shared__ u16 lx[64 * 136];
  int c = tid >> 1, x0 = (tid & 1) * 32;
  const float* src = x + (((size_t)(b * 128 + c)) << 12) + y * 64 + x0;
  float s0 = sc[c], o0 = off[c];
  #pragma unroll
  for (int i = 0; i < 32; i += 4) {
    f32x4 v = *(const f32x4*)(src + i);
    #pragma unroll
    for (int j = 0; j < 4; ++j) {
      int xc = x0 + i + j;
      float yv = s0 * v[j] + o0;
      ls[xc * 144 + c] = sgn8(yv);
      lx[xc * 136 + c] = f2bf(v[j]);
    }
  }
  __syncthreads();
  int xx = tid >> 2, cg = (tid & 3) * 32;
  u8*  pdst = a1p + ((size_t)b * 4356 + (y + 1) * 66 + xx + 1) * 128 + cg;
  u16* xdst = xb + ((size_t)blockIdx.x * 64 + xx) * 128 + cg;
  *(i32x4*)(pdst)      = *(const i32x4*)&ls[xx * 144 + cg];
  *(i32x4*)(pdst + 16) = *(const i32x4*)&ls[xx * 144 + cg + 16];
  #pragma unroll
  for (int i = 0; i < 32; i += 8)
    *(i32x4*)(xdst + i) = *(const i32x4*)&lx[xx * 136 + cg + i];
}

// -------- binact2: h [m][256] f32 -> a2p i8 planes [b*2+c2][66][66][128] --------
__global__ void binact2(const float* __restrict__ h, const float* __restrict__ sc,
                        const float* __restrict__ off, u8* __restrict__ a2p) {
  int b = blockIdx.x >> 6, y = blockIdx.x & 63, tid = threadIdx.x;
  __shared__ float s_sc[256], s_off[256];
  s_sc[tid] = sc[tid]; s_off[tid] = off[tid];
  __syncthreads();
  const f32x4* src = (const f32x4*)(h + (size_t)blockIdx.x * 16384);
  #pragma unroll 4
  for (int i = tid; i < 4096; i += 256) {
    f32x4 v = src[i];
    int px = i >> 6, c0 = (i & 63) * 4;
    int c2 = c0 >> 7, chm = c0 & 127;
    uint32_t p = (uint32_t)sgn8(s_sc[c0 + 0] * v[0] + s_off[c0 + 0]) |
                 ((uint32_t)sgn8(s_sc[c0 + 1] * v[1] + s_off[c0 + 1]) << 8) |
                 ((uint32_t)sgn8(s_sc[c0 + 2] * v[2] + s_off[c0 + 2]) << 16) |
                 ((uint32_t)sgn8(s_sc[c0 + 3] * v[3] + s_off[c0 + 3]) << 24);
    u8* dst = a2p + ((size_t)(b * 2 + c2) * 4356 + (y + 1) * 66 + px + 1) * 128 + chm;
    *(uint32_t*)dst = p;
  }
}

// ---------------- i8 implicit-GEMM conv, wave-private-B barrier-free loop ----------------
// M=64 (1 image row), N=256, 256 thr = 4 waves (1M x 4N), 66.5 KB LDS, 2 blocks/CU.
// A: [3][66][128ch] i8 window (pre-swizzled-source GLL), read-only after load.
// B: each wave GLLs ONLY its own wn-region of the dbuf and reads ONLY that region
//    -> all B hazards intra-wave (program order + own vmcnt). ZERO barriers in
//    conv1's loop; conv2 drains once per chunk boundary. B staged 2 steps deep.
template <int NCHUNK, bool SKIP, bool ADD_TEMB, bool STATS, bool DIRECT>
__global__ __launch_bounds__(256, 2) void convk(
    const u8* __restrict__ Apl, const u16* __restrict__ xb,
    const u8* __restrict__ wS, const u16* __restrict__ wskB,
    const float* __restrict__ alpha, const float* __restrict__ temb,
    float* __restrict__ outp, float* __restrict__ pS, float* __restrict__ pQ) {
  constexpr int NS = NCHUNK * 18;
  __shared__ u8 smem[66560];
  u8* lA = smem;            // 25344 B window; rest/epilogue scratch
  u8* lB = smem + 25344;    // 2 x 16384 B
  const int tid = threadIdx.x;
  const int lane = tid & 63, wn = tid >> 6;
  const int kq = lane >> 4, li = lane & 15;

  const int bid = blockIdx.x;
  const int tile = (bid & 7) * 256 + (bid >> 3);   // XCD-chunked swizzle (2048%8==0)
  const int m0 = tile * 64;
  const int b = tile >> 6, y = tile & 63;

  // ---- B: wave-private region GLL ----
  auto issueB = [&](int s) {
    const u8* src = wS + (size_t)s * 16384 + wn * 4096 + lane * 16;
    u8* dst = lB + (s & 1) * 16384 + wn * 4096;
    #pragma unroll
    for (int i = 0; i < 4; ++i) GLL(src + i * 1024, dst + i * 1024);
  };

  // ---- A window: 1584 granules, linear dest + pre-swizzled source ----
  auto winLoad = [&](int c) {
    const u8* gp = Apl + (size_t)(b * NCHUNK + c) * 557568 + (size_t)y * 8448;
    #pragma unroll
    for (int k = 0; k < 6; ++k) {
      int g = tid + k * 256;
      int row = g / 528, rem = g - row * 528;
      int px = rem >> 3, sl = rem & 7;
      const u8* src = gp + (size_t)(row * 66 + px) * 128 + ((sl ^ (px & 7)) << 4);
      u8* dst = lA + (size_t)((tid & ~63) + k * 256) * 16;
      GLL(src, dst);
    }
    if (tid < 48) {
      int g = 1536 + tid;
      int rem = g - 1056;              // row 2
      int px = rem >> 3, sl = rem & 7;
      const u8* src = gp + (size_t)(2 * 66 + px) * 128 + ((sl ^ (px & 7)) << 4);
      GLL(src, lA + (size_t)1536 * 16);
    }
  };

  // ---- fragment base pointers ----
  const u8* pA[3][2];
  #pragma unroll
  for (int dx = 0; dx < 3; ++dx)
    #pragma unroll
    for (int cc = 0; cc < 2; ++cc)
      pA[dx][cc] = lA + (li + dx) * 128 +
                   ((((cc << 2) + kq) ^ ((li + dx) & 7)) << 4);
  const u8* pB = lB + wn * 4096 + li * 64 + ((kq ^ (li & 3)) << 4);

  i32x4 acc[4][4] = {};

  auto compute = [&](int dy, int dx, int cc, int buf) {
    i32x4 av[4], bv[4];
    #pragma unroll
    for (int f = 0; f < 4; ++f)
      av[f] = *(const i32x4*)(pA[dx][cc] + dy * 8448 + f * 2048);
    #pragma unroll
    for (int f = 0; f < 4; ++f)
      bv[f] = *(const i32x4*)(pB + buf * 16384 + f * 1024);
    __builtin_amdgcn_s_setprio(1);
    #pragma unroll
    for (int mf = 0; mf < 4; ++mf)
      #pragma unroll
      for (int nf = 0; nf < 4; ++nf)
        acc[mf][nf] = __builtin_amdgcn_mfma_i32_16x16x64_i8(
            av[mf], bv[nf], acc[mf][nf], 0, 0, 0);
    __builtin_amdgcn_s_setprio(0);
  };

  // ---- prologue: window 0 + B(0), B(1) ----
  winLoad(0);
  issueB(0);
  issueB(1);
  VM4;                 // window + B(0) landed; B(1) may be in flight
  BAR;                 // publish window

  // ---- main loop: barrier-free (conv1); one drain per chunk boundary (conv2) ----
  #pragma unroll
  for (int s = 0; s < NS; ++s) {
    if (NCHUNK > 1 && s > 0 && (s % 18) == 0) {
      LGKM0; BAR;               // all waves done reading old window
      winLoad(s / 18);
      VM0; BAR;                 // new window (and all B in flight) landed
    }
    const int t = s % 18, cc = t & 1, tap = t >> 1;
    if (s + 2 < NS) { VM4; } else { VM0; }   // B(s) landed
    compute(tap / 3, tap % 3, cc, s & 1);
    LGKM0;                                    // my reads of lB[s&1] complete
    if (s + 2 < NS) issueB(s + 2);            // safe: writes lB[s&1], wave-private
  }

  f32x4 facc[4][4];
  if constexpr (SKIP) {
    #pragma unroll
    for (int mf = 0; mf < 4; ++mf)
      #pragma unroll
      for (int nf = 0; nf < 4; ++nf)
        #pragma unroll
        for (int r = 0; r < 4; ++r)
          facc[mf][nf][r] = (float)acc[mf][nf][r];
    const u8* pAs[2];
    const u8* pBs[2];
    #pragma unroll
    for (int ks = 0; ks < 2; ++ks) {
      pAs[ks] = lA + li * 128 + ((((ks << 2) + kq) ^ (li & 7)) << 4);
      pBs[ks] = lB + (wn * 64 + li) * 128 + ((((ks << 2) + kq) ^ (li & 7)) << 4);
    }
    LGKM0; BAR;                   // lA/lB free to overwrite
    #pragma unroll
    for (int e = 0; e < 2; ++e) {
      // stage skip-A (xb e-half, pre-swizzled source) into lA: 512 granules
      #pragma unroll
      for (int k = 0; k < 2; ++k) {
        int g = tid + k * 256;
        int m = g >> 3, sl = g & 7;
        const u8* src = (const u8*)xb + (size_t)(m0 + m) * 256 + e * 128 +
                        ((sl ^ (m & 7)) << 4);
        u8* dst = lA + (size_t)((tid & ~63) + k * 256) * 16;
        GLL(src, dst);
      }
      // stage skip-B into regs then swizzled LDS: 2048 granules
      i32x4 rS[8];
      const i32x4* gs = (const i32x4*)((const u8*)wskB + (size_t)e * 32768) + tid;
      #pragma unroll
      for (int k = 0; k < 8; ++k) rS[k] = gs[k * 256];
      VM0;
      #pragma unroll
      for (int k = 0; k < 8; ++k) {
        int g = tid + k * 256;
        int o = g >> 3, sl = g & 7;
        *(i32x4*)(lB + o * 128 + ((sl ^ (o & 7)) << 4)) = rS[k];
      }
      LGKM0; BAR;
      #pragma unroll
      for (int ks = 0; ks < 2; ++ks) {
        short8 av[4], bv[4];
        #pragma unroll
        for (int f = 0; f < 4; ++f) av[f] = *(const short8*)(pAs[ks] + f * 2048);
        #pragma unroll
        for (int f = 0; f < 4; ++f) bv[f] = *(const short8*)(pBs[ks] + f * 2048);
        __builtin_amdgcn_s_setprio(1);
        #pragma unroll
        for (int mf = 0; mf < 4; ++mf)
          #pragma unroll
          for (int nf = 0; nf < 4; ++nf)
            facc[mf][nf] = __builtin_amdgcn_mfma_f32_16x16x32_bf16(
                av[mf], bv[ks * 4 + nf - ks * 4 + nf == nf ? nf : nf], facc[mf][nf], 0, 0, 0);
        __builtin_amdgcn_s_setprio(0);
      }
      if (e == 0) { LGKM0; BAR; }
    }
  }

  const int cb = wn * 64 + li;

  if constexpr (STATS) {
    float als[4], tas[4];
    #pragma unroll
    for (int nf = 0; nf < 4; ++nf) {
      int o = cb + nf * 16;
      als[nf] = alpha[o];
      tas[nf] = ADD_TEMB ? temb[b * 256 + o] : 0.f;
    }
    // per-block BN2 partials (each wave owns its 64 o-cols over all 64 rows)
    float ps[4] = {0.f, 0.f, 0.f, 0.f}, pq[4] = {0.f, 0.f, 0.f, 0.f};
    #pragma unroll
    for (int nf = 0; nf < 4; ++nf)
      #pragma unroll
      for (int mf = 0; mf < 4; ++mf)
        #pragma unroll
        for (int r = 0; r < 4; ++r) {
          float v = (float)acc[mf][nf][r] * als[nf] + tas[nf];
          ps[nf] += v; pq[nf] += v * v;
        }
    #pragma unroll
    for (int nf = 0; nf < 4; ++nf) {
      ps[nf] += __shfl_xor(ps[nf], 16); ps[nf] += __shfl_xor(ps[nf], 32);
      pq[nf] += __shfl_xor(pq[nf], 16); pq[nf] += __shfl_xor(pq[nf], 32);
    }
    if (lane < 16) {
      #pragma unroll
      for (int nf = 0; nf < 4; ++nf) {
        pS[(size_t)bid * 256 + wn * 64 + nf * 16 + lane] = ps[nf];
        pQ[(size_t)bid * 256 + wn * 64 + nf * 16 + lane] = pq[nf];
      }
    }
    __syncthreads();
    // restage h tile [64][256] f32 through LDS for full-line coalesced stores
    float* ld = (float*)smem;
    {
      int colg0_base = cb >> 2, c3 = li & 3;
      #pragma unroll
      for (int nf = 0; nf < 4; ++nf) {
        int colg0 = colg0_base + nf * 4;
        #pragma unroll
        for (int mf = 0; mf < 4; ++mf)
          #pragma unroll
          for (int r = 0; r < 4; ++r) {
            int rloc = mf * 16 + 4 * kq + r;
            float v = (float)acc[mf][nf][r] * als[nf] + tas[nf];
            ld[rloc * 256 + ((colg0 ^ kq) << 2) + c3] = v;
          }
      }
    }
    __syncthreads();
    #pragma unroll
    for (int it = 0; it < 16; ++it) {
      int flat = tid + it * 256;
      int row = flat >> 6, c4 = flat & 63;
      int c4p = c4 ^ ((row >> 2) & 3);
      f32x4 v = *(const f32x4*)&ld[row * 256 + c4p * 4];
      *(f32x4*)(outp + (size_t)(m0 + row) * 256 + c4 * 4) = v;
    }
  } else if constexpr (DIRECT) {
    // NCHW transpose epilogue: [64 m][65] tile per 64-ch quarter
    float* tb2 = (float*)lA;
    float* obase = outp + (((size_t)(b * 256)) << 12) + (m0 & 4095);
    __syncthreads();
    #pragma unroll 1
    for (int c4 = 0; c4 < 4; ++c4) {
      if (wn == c4) {
        #pragma unroll
        for (int nf = 0; nf < 4; ++nf) {
          float al = alpha[c4 * 64 + nf * 16 + li];
          #pragma unroll
          for (int mf = 0; mf < 4; ++mf) {
            int cs = (li + nf * 16) ^ ((mf >> 1) & 3);
            #pragma unroll
            for (int r = 0; r < 4; ++r)
              tb2[(mf * 16 + 4 * kq + r) * 65 + cs] = facc[mf][nf][r] * al;
          }
        }
      }
      __syncthreads();
      #pragma unroll
      for (int it = 0; it < 4; ++it) {
        int flat = tid + it * 256;
        int ch = flat >> 4, mg = flat & 15;
        int chs = ch ^ ((mg >> 3) & 3);
        f32x4 v;
        #pragma unroll
        for (int e = 0; e < 4; ++e) v[e] = tb2[(mg * 4 + e) * 65 + chs];
        *(f32x4*)(obase + (((size_t)(c4 * 64 + ch)) << 12) + mg * 4) = v;
      }
      __syncthreads();
    }
  }
}

extern "C" void kernel_launch(void* const* d_in, const int* in_sizes, int n_in,
                              void* d_out, int out_size, void* d_ws, size_t ws_size,
                              hipStream_t stream) {
  const float* x      = (const float*)d_in[0];
  const float* t      = (const float*)d_in[1];
  const float* w1     = (const float*)d_in[2];
  const float* w2     = (const float*)d_in[3];
  const float* wskip  = (const float*)d_in[4];
  const float* gamma1 = (const float*)d_in[5];
  const float* beta1  = (const float*)d_in[6];
  const float* gamma2 = (const float*)d_in[7];
  const float* beta2  = (const float*)d_in[8];
  const float* tw     = (const float*)d_in[9];
  const float* tb     = (const float*)d_in[10];
  float* out = (float*)d_out;

  uint8_t* base = (uint8_t*)d_ws;
  size_t off = 0;
  auto alloc = [&](size_t bytes) {
    void* p = base + off;
    off += (bytes + 255) & ~(size_t)255;
    return p;
  };
  // 96 i8 planes of [66][66][128]: first 32 = a1p, next 64 = a2p
  u8* Abuf     = (u8*)alloc((size_t)96 * 557568);
  u8* a1p      = Abuf;
  u8* a2p      = Abuf + (size_t)32 * 557568;
  u16* xb      = (u16*)alloc((size_t)131072 * 128 * 2);
  float* h     = (float*)alloc((size_t)131072 * 256 * 4);
  u8* w1s      = (u8*)alloc((size_t)18 * 16384);
  u8* w2s      = (u8*)alloc((size_t)36 * 16384);
  u16* wskB    = (u16*)alloc((size_t)2 * 16384 * 2);
  float* temb  = (float*)alloc(32 * 256 * 4);
  float* alpha1 = (float*)alloc(256 * 4);
  float* alpha2 = (float*)alloc(256 * 4);
  float* p1    = (float*)alloc(1024 * 4);
  float* pS    = (float*)alloc((size_t)2048 * 256 * 4);
  float* pQ    = (float*)alloc((size_t)2048 * 256 * 4);
  float* sc1   = (float*)alloc(128 * 4);
  float* off1  = (float*)alloc(128 * 4);
  float* sc2   = (float*)alloc(256 * 4);
  float* off2  = (float*)alloc(256 * 4);

  border_zero<<<96, 256, 0, stream>>>(Abuf);

  bn1_stage1<<<512, 256, 0, stream>>>(x, p1);
  bn1_stage2<<<1, 128, 0, stream>>>(p1, gamma1, beta1, sc1, off1);
  prep_weights<<<256, 256, 0, stream>>>(w1, w2, wskip, w1s, w2s, wskB, alpha1, alpha2);
  temb_k<<<32, 256, 0, stream>>>(t, tw, tb, temb);
  binact1<<<2048, 256, 0, stream>>>(x, sc1, off1, a1p, xb);

  // conv1: i8, barrier-free loop, writes h + BN2 per-block partials
  convk<1, false, true, true, false><<<2048, 256, 0, stream>>>(
      a1p, xb, w1s, (const u16*)nullptr, alpha1, temb, h, pS, pQ);

  bn2_stage2b<<<256, 256, 0, stream>>>(pS, pQ, gamma2, beta2, sc2, off2);
  binact2<<<2048, 256, 0, stream>>>(h, sc2, off2, a2p);

  // conv2: i8 + bf16 skip tail, direct NCHW output
  convk<2, true, false, false, true><<<2048, 256, 0, stream>>>(
      a2p, xb, w2s, wskB, alpha2, (const float*)nullptr, out,
      (float*)nullptr, (float*)nullptr);

  (void)in_sizes; (void)n_in; (void)out_size; (void)ws_size;
}